// Round 3
// baseline (133.205 us; speedup 1.0000x reference)
//
#include <hip/hip_runtime.h>

typedef __attribute__((ext_vector_type(8))) short short8;
typedef __attribute__((ext_vector_type(4))) float f32x4;

#define NB 8
#define LQ 2048
#define LK 2048
#define DIN 1024
#define MROWS (NB * LQ)   // 16384

static constexpr float KSCALE = 0.022097086912079608f; // 1/sqrt(2048)

__device__ __forceinline__ ushort f2bf(float f) {
    union { float f; unsigned int u; } v; v.f = f;
    unsigned int r = v.u + 0x7FFFu + ((v.u >> 16) & 1u);   // RNE
    return (ushort)(r >> 16);
}
__device__ __forceinline__ float bf2f(ushort u) {
    union { unsigned int u; float f; } v; v.u = ((unsigned int)u) << 16;
    return v.f;
}

// ---------------------------------------------------------------------------
// prep: Wt[p][n][k] = bf16(W_p[k][n])  (transpose+convert, LDS tiled)
// ---------------------------------------------------------------------------
__global__ __launch_bounds__(256) void prep_kernel(
    const float* __restrict__ Wq, const float* __restrict__ Wk,
    const float* __restrict__ Wv, ushort* __restrict__ Wt)
{
    const float* W = (blockIdx.z == 0) ? Wq : (blockIdx.z == 1) ? Wk : Wv;
    ushort* O = Wt + (size_t)blockIdx.z * 128 * 1024;
    const int k0 = blockIdx.x * 64, n0 = blockIdx.y * 64;
    __shared__ float tile[64][65];
    const int t = threadIdx.x;
    {
        const int r = t >> 4, c = (t & 15) * 4;
        #pragma unroll
        for (int i = 0; i < 4; ++i) {
            float4 v = *(const float4*)&W[(size_t)(k0 + r + i * 16) * 128 + n0 + c];
            tile[r + i * 16][c + 0] = v.x; tile[r + i * 16][c + 1] = v.y;
            tile[r + i * 16][c + 2] = v.z; tile[r + i * 16][c + 3] = v.w;
        }
    }
    __syncthreads();
    {
        const int n = t >> 2, kc = (t & 3) * 16;
        ushort tmp[16];
        #pragma unroll
        for (int j = 0; j < 16; ++j) tmp[j] = f2bf(tile[kc + j][n]);
        *(uint4*)&O[(size_t)(n0 + n) * 1024 + k0 + kc]     = *(uint4*)&tmp[0];
        *(uint4*)&O[(size_t)(n0 + n) * 1024 + k0 + kc + 8] = *(uint4*)&tmp[8];
    }
}

// ---------------------------------------------------------------------------
// proj: Y = bf16(relu(X[16384,1024] @ W + b))
// 64x128 tile, grid (256,3) = 768 blocks (3/CU), 4 waves (2x2 of 32x64),
// BK=64, double-buffered LDS (48 KB), loads pipelined 2 steps ahead.
// ---------------------------------------------------------------------------
__global__ __launch_bounds__(256, 3) void proj_kernel(
    const float* __restrict__ Xq, const float* __restrict__ bq,
    const float* __restrict__ Xk, const float* __restrict__ bk,
    const float* __restrict__ Xv, const float* __restrict__ bv,
    const ushort* __restrict__ Wt,
    ushort* __restrict__ qp, ushort* __restrict__ kp, ushort* __restrict__ vp)
{
    const int p = blockIdx.y;
    const float* X; const float* bias; ushort* Y;
    if (p == 0)      { X = Xq; bias = bq; Y = qp; }
    else if (p == 1) { X = Xk; bias = bk; Y = kp; }
    else             { X = Xv; bias = bv; Y = vp; }
    const ushort* W = Wt + (size_t)p * 128 * 1024;

    __shared__ __align__(16) ushort AsB[2][64 * 64];    // 16 KB
    __shared__ __align__(16) ushort BsB[2][128 * 64];   // 32 KB

    const int tid  = threadIdx.x;
    const int lane = tid & 63;
    const int w    = tid >> 6;
    const int wr   = (w >> 1) * 32;
    const int wc   = (w & 1) * 64;
    const int row0 = blockIdx.x * 64;

    // staging: X 64 rows x 64 k fp32 (4 threads/row, 16 k each)
    //          W 128 rows x 64 k bf16 (2 threads/row, 32 k each)
    const int ar = tid >> 2, ak = (tid & 3) * 16;
    const int br = tid >> 1, bkk = (tid & 1) * 32;
    const float*  Xp = X + (size_t)(row0 + ar) * DIN + ak;
    const ushort* Wp = W + (size_t)br * DIN + bkk;
    const int abase = ar * 64 + ak,  aswz = (ar & 7) << 3;
    const int bbase = br * 64 + bkk, bswz = (br & 7) << 3;

    // fragment indices
    const int col  = lane & 15;
    const int kg   = (lane >> 4) * 8;
    const int fswz = (col & 7) << 3;

    float4 xa[2][4];
    uint4  wb[2][4];
    f32x4  acc[2][4];
    #pragma unroll
    for (int mi = 0; mi < 2; ++mi)
        #pragma unroll
        for (int ni = 0; ni < 4; ++ni)
            acc[mi][ni] = (f32x4){0.f, 0.f, 0.f, 0.f};

#define STEP_LOAD(r_, kc_) do {                                               \
    _Pragma("unroll") for (int j = 0; j < 4; ++j)                             \
        xa[r_][j] = *(const float4*)&Xp[(kc_) + j * 4];                       \
    _Pragma("unroll") for (int j = 0; j < 4; ++j)                             \
        wb[r_][j] = *(const uint4*)&Wp[(kc_) + j * 8];                        \
} while (0)

#define STEP_WRITE(b_) do {                                                   \
    _Pragma("unroll") for (int j = 0; j < 2; ++j) {                           \
        uint4 u;                                                              \
        u.x = (unsigned)f2bf(xa[b_][2*j].x)   | ((unsigned)f2bf(xa[b_][2*j].y)   << 16); \
        u.y = (unsigned)f2bf(xa[b_][2*j].z)   | ((unsigned)f2bf(xa[b_][2*j].w)   << 16); \
        u.z = (unsigned)f2bf(xa[b_][2*j+1].x) | ((unsigned)f2bf(xa[b_][2*j+1].y) << 16); \
        u.w = (unsigned)f2bf(xa[b_][2*j+1].z) | ((unsigned)f2bf(xa[b_][2*j+1].w) << 16); \
        *(uint4*)&AsB[b_][(abase + j * 8) ^ aswz] = u;                        \
    }                                                                         \
    _Pragma("unroll") for (int j = 0; j < 4; ++j)                             \
        *(uint4*)&BsB[b_][(bbase + j * 8) ^ bswz] = wb[b_][j];                \
} while (0)

#define STEP_MFMA(b_) do {                                                    \
    _Pragma("unroll") for (int kk = 0; kk < 2; ++kk) {                        \
        const int kb = kk * 32 + kg;                                          \
        short8 af[2], bfr[4];                                                 \
        _Pragma("unroll") for (int mi = 0; mi < 2; ++mi)                      \
            af[mi] = *(const short8*)&AsB[b_][((wr + mi * 16 + col) * 64 + kb) ^ fswz]; \
        _Pragma("unroll") for (int ni = 0; ni < 4; ++ni)                      \
            bfr[ni] = *(const short8*)&BsB[b_][((wc + ni * 16 + col) * 64 + kb) ^ fswz]; \
        _Pragma("unroll") for (int mi = 0; mi < 2; ++mi)                      \
            _Pragma("unroll") for (int ni = 0; ni < 4; ++ni)                  \
                acc[mi][ni] = __builtin_amdgcn_mfma_f32_16x16x32_bf16(        \
                    af[mi], bfr[ni], acc[mi][ni], 0, 0, 0);                   \
    }                                                                         \
} while (0)

    // prologue: step0 -> buf0, step1 -> regs[1]
    STEP_LOAD(0, 0);
    STEP_WRITE(0);
    STEP_LOAD(1, 64);
    __syncthreads();

    #pragma unroll 2
    for (int k = 0; k < 14; ++k) {
        const int cur = k & 1, nxt = cur ^ 1;
        STEP_LOAD(cur, (k + 2) * 64);   // step k+2 into just-freed regs
        STEP_WRITE(nxt);                // step k+1 regs -> buf[nxt]
        STEP_MFMA(cur);                 // compute step k
        __syncthreads();
    }
    // k = 14: no more loads
    STEP_WRITE(1);
    STEP_MFMA(0);
    __syncthreads();
    // k = 15
    STEP_MFMA(1);
    __syncthreads();                    // LDS free for epilogue reuse

#undef STEP_LOAD
#undef STEP_WRITE
#undef STEP_MFMA

    float bb[4];
    #pragma unroll
    for (int ni = 0; ni < 4; ++ni) bb[ni] = bias[wc + ni * 16 + col];

    ushort* Ys = (ushort*)AsB;          // 64*128 ushorts = 16 KB
    const int orow4 = (lane >> 4) * 4;
    #pragma unroll
    for (int mi = 0; mi < 2; ++mi)
        #pragma unroll
        for (int ni = 0; ni < 4; ++ni)
            #pragma unroll
            for (int j = 0; j < 4; ++j) {
                float v = fmaxf(acc[mi][ni][j] + bb[ni], 0.f);
                const int rl = wr + mi * 16 + orow4 + j;
                const int cl = wc + ni * 16 + col;
                Ys[(rl * 128 + cl) ^ ((rl & 15) << 3)] = f2bf(v);
            }
    __syncthreads();

    {
        const int r = tid >> 2, c = (tid & 3) * 32;
        const int swz = (r & 15) << 3;
        ushort* Yg = Y + (size_t)(row0 + r) * 128 + c;
        #pragma unroll
        for (int j = 0; j < 4; ++j)
            *(uint4*)&Yg[j * 8] = *(const uint4*)&Ys[(r * 128 + c + j * 8) ^ swz];
    }
}

// ---------------------------------------------------------------------------
// ktv: per (batch, 64-row chunk): partial Mt_part[v][e] = sum_r v[r][v]*k[r][e]
// ---------------------------------------------------------------------------
__global__ __launch_bounds__(256) void ktv_kernel(
    const ushort* __restrict__ kp, const ushort* __restrict__ vp,
    ushort* __restrict__ part)
{
    const int b = blockIdx.y, chunk = blockIdx.x;
    const ushort* K = kp + ((size_t)b * LK + chunk * 64) * 128;
    const ushort* V = vp + ((size_t)b * LK + chunk * 64) * 128;
    ushort* P = part + ((size_t)(b * 32 + chunk)) * 16384;

    __shared__ __align__(16) ushort ks[64 * 128];
    __shared__ __align__(16) ushort vs[64 * 128];
    const int t = threadIdx.x;
    {
        const int r = t >> 2, cc = (t & 3) * 32;
        #pragma unroll
        for (int j = 0; j < 4; ++j) {
            *(uint4*)&ks[r * 128 + cc + j * 8] = *(const uint4*)&K[r * 128 + cc + j * 8];
            *(uint4*)&vs[r * 128 + cc + j * 8] = *(const uint4*)&V[r * 128 + cc + j * 8];
        }
    }
    __syncthreads();

    const int e0 = (t & 15) * 8;
    const int v0 = (t >> 4) * 8;
    float acc[8][8];
    #pragma unroll
    for (int i = 0; i < 8; ++i)
        #pragma unroll
        for (int j = 0; j < 8; ++j) acc[i][j] = 0.f;

    for (int r = 0; r < 64; ++r) {
        uint4 kf = *(const uint4*)&ks[r * 128 + e0];
        uint4 vf = *(const uint4*)&vs[r * 128 + v0];
        const ushort* kw = (const ushort*)&kf;
        const ushort* vw = (const ushort*)&vf;
        float ke[8], ve[8];
        #pragma unroll
        for (int j = 0; j < 8; ++j) { ke[j] = bf2f(kw[j]); ve[j] = bf2f(vw[j]); }
        #pragma unroll
        for (int i = 0; i < 8; ++i)
            #pragma unroll
            for (int j = 0; j < 8; ++j)
                acc[i][j] = fmaf(ve[i], ke[j], acc[i][j]);
    }

    #pragma unroll
    for (int i = 0; i < 8; ++i) {
        ushort tmp[8];
        #pragma unroll
        for (int j = 0; j < 8; ++j) tmp[j] = f2bf(acc[i][j]);
        *(uint4*)&P[(v0 + i) * 128 + e0] = *(uint4*)&tmp[0];
    }
}

// ---------------------------------------------------------------------------
// reduce: Mt[b][v*128+e] = bf16(KSCALE * sum_{c<32} part[b][c][v*128+e])
// ---------------------------------------------------------------------------
__global__ __launch_bounds__(256) void reduce_kernel(
    const ushort* __restrict__ part, ushort* __restrict__ Mt)
{
    const int g = blockIdx.x * 256 + threadIdx.x;
    const int b = g >> 14, idx = g & 16383;
    const ushort* P = part + (size_t)b * 32 * 16384 + idx;
    float s = 0.f;
    #pragma unroll
    for (int c = 0; c < 32; ++c) s += bf2f(P[(size_t)c * 16384]);
    Mt[g] = f2bf(s * KSCALE);
}

// ---------------------------------------------------------------------------
// qm: out[row][v] = sum_e qp[row][e] * Mt[b][v][e]
// ---------------------------------------------------------------------------
__global__ __launch_bounds__(256) void qm_kernel(
    const ushort* __restrict__ qp, const ushort* __restrict__ Mt,
    float* __restrict__ out)
{
    const int row0 = blockIdx.x * 64;
    const int b = row0 >> 11;
    const ushort* Q = qp + (size_t)row0 * 128;
    const ushort* M = Mt + (size_t)b * 16384;

    __shared__ __align__(16) ushort As[64 * 128];
    __shared__ __align__(16) ushort Bs[128 * 128];

    const int t = threadIdx.x;
    {
        const int r = t >> 2, cc = (t & 3) * 32;
        const int swz = (r & 15) << 3;
        #pragma unroll
        for (int j = 0; j < 4; ++j)
            *(uint4*)&As[(r * 128 + cc + j * 8) ^ swz] = *(const uint4*)&Q[r * 128 + cc + j * 8];
    }
    {
        const int r = t >> 1, cc = (t & 1) * 64;
        const int swz = (r & 15) << 3;
        #pragma unroll
        for (int j = 0; j < 8; ++j)
            *(uint4*)&Bs[(r * 128 + cc + j * 8) ^ swz] = *(const uint4*)&M[r * 128 + cc + j * 8];
    }
    __syncthreads();

    const int lane = t & 63;
    const int wcol = (t >> 6) * 32;
    const int col  = lane & 15;
    const int kgrp = (lane >> 4) * 8;
    const int fswz = col << 3;

    f32x4 acc[4][2];
    #pragma unroll
    for (int mi = 0; mi < 4; ++mi)
        #pragma unroll
        for (int ni = 0; ni < 2; ++ni)
            acc[mi][ni] = (f32x4){0.f, 0.f, 0.f, 0.f};

    #pragma unroll
    for (int kk = 0; kk < 4; ++kk) {
        const int kb = kk * 32 + kgrp;
        short8 af[4], bfv[2];
        #pragma unroll
        for (int mi = 0; mi < 4; ++mi)
            af[mi] = *(const short8*)&As[((mi * 16 + col) * 128 + kb) ^ fswz];
        #pragma unroll
        for (int ni = 0; ni < 2; ++ni)
            bfv[ni] = *(const short8*)&Bs[((wcol + ni * 16 + col) * 128 + kb) ^ fswz];
        #pragma unroll
        for (int mi = 0; mi < 4; ++mi)
            #pragma unroll
            for (int ni = 0; ni < 2; ++ni)
                acc[mi][ni] = __builtin_amdgcn_mfma_f32_16x16x32_bf16(
                    af[mi], bfv[ni], acc[mi][ni], 0, 0, 0);
    }

    const int orow = (lane >> 4) * 4;
    #pragma unroll
    for (int mi = 0; mi < 4; ++mi)
        #pragma unroll
        for (int ni = 0; ni < 2; ++ni)
            #pragma unroll
            for (int j = 0; j < 4; ++j)
                out[(size_t)(row0 + mi * 16 + orow + j) * 128 + wcol + ni * 16 + col] =
                    acc[mi][ni][j];
}

// ---------------------------------------------------------------------------
extern "C" void kernel_launch(void* const* d_in, const int* in_sizes, int n_in,
                              void* d_out, int out_size, void* d_ws, size_t ws_size,
                              hipStream_t stream)
{
    const float* query = (const float*)d_in[0];
    const float* key   = (const float*)d_in[1];
    const float* value = (const float*)d_in[2];
    const float* Wq    = (const float*)d_in[3];
    const float* bq    = (const float*)d_in[4];
    const float* Wk    = (const float*)d_in[5];
    const float* bk    = (const float*)d_in[6];
    const float* Wv    = (const float*)d_in[7];
    const float* bv    = (const float*)d_in[8];
    float* out = (float*)d_out;

    ushort* qp   = (ushort*)d_ws;                    // 16384*128 bf16
    ushort* kp   = qp + (size_t)MROWS * 128;
    ushort* vp   = kp + (size_t)MROWS * 128;
    ushort* Wt   = vp + (size_t)MROWS * 128;         // 3*128*1024 bf16
    ushort* part = Wt + (size_t)3 * 128 * 1024;      // 8*32*16384 bf16
    ushort* Mt   = part + (size_t)8 * 32 * 16384;    // 8*16384 bf16

    dim3 blk(256);
    prep_kernel<<<dim3(16, 2, 3), blk, 0, stream>>>(Wq, Wk, Wv, Wt);
    proj_kernel<<<dim3(256, 3), blk, 0, stream>>>(query, bq, key, bk, value, bv,
                                                  Wt, qp, kp, vp);
    ktv_kernel<<<dim3(32, NB), blk, 0, stream>>>(kp, vp, part);
    reduce_kernel<<<512, blk, 0, stream>>>(part, Mt);
    qm_kernel<<<MROWS / 64, blk, 0, stream>>>(qp, Mt, out);
}

// Round 4
// 70.803 us; speedup vs baseline: 1.8813x; 1.8813x over previous
//
#include <hip/hip_runtime.h>
#include <hip/hip_bf16.h>

typedef __attribute__((ext_vector_type(8))) short short8;
typedef __attribute__((ext_vector_type(4))) float f32x4;

#define NB 8
#define LQ 2048
#define LK 2048
#define DIN 1024
#define MROWS (NB * LQ)   // 16384

static constexpr float KSCALE = 0.022097086912079608f; // 1/sqrt(2048)

__device__ __forceinline__ ushort f2bf(float f) {
    union { float f; unsigned int u; } v; v.f = f;
    unsigned int r = v.u + 0x7FFFu + ((v.u >> 16) & 1u);   // RNE
    return (ushort)(r >> 16);
}
__device__ __forceinline__ float bf2f(ushort u) {
    union { unsigned int u; float f; } v; v.u = ((unsigned int)u) << 16;
    return v.f;
}
__device__ __forceinline__ unsigned pk2(float lo, float hi) {
    __hip_bfloat162 h = __float22bfloat162_rn(float2{lo, hi});   // v_cvt_pk_bf16_f32
    union { __hip_bfloat162 h; unsigned u; } c; c.h = h; return c.u;
}

// ---------------------------------------------------------------------------
// prep: Wt[p][n][k] = bf16(W_p[k][n])  (transpose+convert, LDS tiled)
// ---------------------------------------------------------------------------
__global__ __launch_bounds__(256) void prep_kernel(
    const float* __restrict__ Wq, const float* __restrict__ Wk,
    const float* __restrict__ Wv, ushort* __restrict__ Wt)
{
    const float* W = (blockIdx.z == 0) ? Wq : (blockIdx.z == 1) ? Wk : Wv;
    ushort* O = Wt + (size_t)blockIdx.z * 128 * 1024;
    const int k0 = blockIdx.x * 64, n0 = blockIdx.y * 64;
    __shared__ float tile[64][65];
    const int t = threadIdx.x;
    {
        const int r = t >> 4, c = (t & 15) * 4;
        #pragma unroll
        for (int i = 0; i < 4; ++i) {
            float4 v = *(const float4*)&W[(size_t)(k0 + r + i * 16) * 128 + n0 + c];
            tile[r + i * 16][c + 0] = v.x; tile[r + i * 16][c + 1] = v.y;
            tile[r + i * 16][c + 2] = v.z; tile[r + i * 16][c + 3] = v.w;
        }
    }
    __syncthreads();
    {
        const int n = t >> 2, kc = (t & 3) * 16;
        ushort tmp[16];
        #pragma unroll
        for (int j = 0; j < 16; ++j) tmp[j] = f2bf(tile[kc + j][n]);
        *(uint4*)&O[(size_t)(n0 + n) * 1024 + k0 + kc]     = *(uint4*)&tmp[0];
        *(uint4*)&O[(size_t)(n0 + n) * 1024 + k0 + kc + 8] = *(uint4*)&tmp[8];
    }
}

// ---------------------------------------------------------------------------
// proj: Y = bf16(relu(X[16384,1024] @ W + b))
// 64x128 tile, grid (256,3) = 768 blocks (3/CU, 12 waves/CU), 4 waves (2x2),
// BK=64, double-buffered LDS (48 KB), T14 single-register-set pipeline:
//   ISSUE(k+1) -> MFMA(k) -> cvt+WRITE(k+1) -> barrier.
// All staging registers statically indexed (rule #20).
// ---------------------------------------------------------------------------
__global__ __launch_bounds__(256, 3) void proj_kernel(
    const float* __restrict__ Xq, const float* __restrict__ bq,
    const float* __restrict__ Xk, const float* __restrict__ bk,
    const float* __restrict__ Xv, const float* __restrict__ bv,
    const ushort* __restrict__ Wt,
    ushort* __restrict__ qp, ushort* __restrict__ kp, ushort* __restrict__ vp)
{
    const int p = blockIdx.y;
    const float* X; const float* bias; ushort* Y;
    if (p == 0)      { X = Xq; bias = bq; Y = qp; }
    else if (p == 1) { X = Xk; bias = bk; Y = kp; }
    else             { X = Xv; bias = bv; Y = vp; }
    const ushort* W = Wt + (size_t)p * 128 * 1024;

    __shared__ __align__(16) ushort AsB[2][64 * 64];    // 16 KB
    __shared__ __align__(16) ushort BsB[2][128 * 64];   // 32 KB

    const int tid  = threadIdx.x;
    const int lane = tid & 63;
    const int w    = tid >> 6;
    const int wr   = (w >> 1) * 32;
    const int wc   = (w & 1) * 64;
    const int row0 = blockIdx.x * 64;

    // X staging: 64 rows x 64 k fp32 (4 threads/row, 16 floats each)
    const int ar = tid >> 2, ak = (tid & 3) * 16;
    const float* Xp = X + (size_t)(row0 + ar) * DIN + ak;
    const int abase = ar * 64 + ak, aswz = (ar & 7) << 3;
    // W staging: 128 rows x 64 k bf16 (2 threads/row, 32 ushorts each)
    const int br = tid >> 1, bkk = (tid & 1) * 32;
    const ushort* Wp = W + (size_t)br * DIN + bkk;
    const int bbase = br * 64 + bkk, bswz = (br & 7) << 3;

    // fragment indices
    const int col  = lane & 15;
    const int kg   = (lane >> 4) * 8;
    const int fswz = (col & 7) << 3;

    float4 xa0, xa1, xa2, xa3;          // single named set — static indices
    uint4  wb0, wb1, wb2, wb3;
    f32x4  acc[2][4];
    #pragma unroll
    for (int mi = 0; mi < 2; ++mi)
        #pragma unroll
        for (int ni = 0; ni < 4; ++ni)
            acc[mi][ni] = (f32x4){0.f, 0.f, 0.f, 0.f};

#define ISSUE(kc_) do {                                                       \
    xa0 = *(const float4*)&Xp[(kc_) + 0];                                     \
    xa1 = *(const float4*)&Xp[(kc_) + 4];                                     \
    xa2 = *(const float4*)&Xp[(kc_) + 8];                                     \
    xa3 = *(const float4*)&Xp[(kc_) + 12];                                    \
    wb0 = *(const uint4*)&Wp[(kc_) + 0];                                      \
    wb1 = *(const uint4*)&Wp[(kc_) + 8];                                      \
    wb2 = *(const uint4*)&Wp[(kc_) + 16];                                     \
    wb3 = *(const uint4*)&Wp[(kc_) + 24];                                     \
} while (0)

#define WRITE(b_) do {                                                        \
    uint4 u0, u1;                                                             \
    u0.x = pk2(xa0.x, xa0.y); u0.y = pk2(xa0.z, xa0.w);                       \
    u0.z = pk2(xa1.x, xa1.y); u0.w = pk2(xa1.z, xa1.w);                       \
    u1.x = pk2(xa2.x, xa2.y); u1.y = pk2(xa2.z, xa2.w);                       \
    u1.z = pk2(xa3.x, xa3.y); u1.w = pk2(xa3.z, xa3.w);                       \
    *(uint4*)&AsB[b_][(abase + 0) ^ aswz] = u0;                               \
    *(uint4*)&AsB[b_][(abase + 8) ^ aswz] = u1;                               \
    *(uint4*)&BsB[b_][(bbase + 0)  ^ bswz] = wb0;                             \
    *(uint4*)&BsB[b_][(bbase + 8)  ^ bswz] = wb1;                             \
    *(uint4*)&BsB[b_][(bbase + 16) ^ bswz] = wb2;                             \
    *(uint4*)&BsB[b_][(bbase + 24) ^ bswz] = wb3;                             \
} while (0)

#define STEP_MFMA(b_) do {                                                    \
    _Pragma("unroll") for (int kk = 0; kk < 2; ++kk) {                        \
        const int kb = kk * 32 + kg;                                          \
        short8 af[2], bfr[4];                                                 \
        _Pragma("unroll") for (int mi = 0; mi < 2; ++mi)                      \
            af[mi] = *(const short8*)&AsB[b_][((wr + mi * 16 + col) * 64 + kb) ^ fswz]; \
        _Pragma("unroll") for (int ni = 0; ni < 4; ++ni)                      \
            bfr[ni] = *(const short8*)&BsB[b_][((wc + ni * 16 + col) * 64 + kb) ^ fswz]; \
        _Pragma("unroll") for (int mi = 0; mi < 2; ++mi)                      \
            _Pragma("unroll") for (int ni = 0; ni < 4; ++ni)                  \
                acc[mi][ni] = __builtin_amdgcn_mfma_f32_16x16x32_bf16(        \
                    af[mi], bfr[ni], acc[mi][ni], 0, 0, 0);                   \
    }                                                                         \
} while (0)

    // prologue: stage step 0 (latency exposed once)
    ISSUE(0);
    WRITE(0);
    __syncthreads();

    for (int k = 0; k < 15; ++k) {
        const int cur = k & 1, nxt = cur ^ 1;   // LDS address select only
        ISSUE((k + 1) * 64);    // loads in flight across the MFMA phase
        STEP_MFMA(cur);
        WRITE(nxt);             // first use of loads -> vmcnt wait lands here
        __syncthreads();
    }
    STEP_MFMA(1);               // step 15
    __syncthreads();            // LDS free for epilogue reuse

#undef ISSUE
#undef WRITE
#undef STEP_MFMA

    float bb[4];
    #pragma unroll
    for (int ni = 0; ni < 4; ++ni) bb[ni] = bias[wc + ni * 16 + col];

    ushort* Ys = (ushort*)AsB;          // 64*128 ushorts = 16 KB
    const int orow4 = (lane >> 4) * 4;
    #pragma unroll
    for (int mi = 0; mi < 2; ++mi)
        #pragma unroll
        for (int ni = 0; ni < 4; ++ni)
            #pragma unroll
            for (int j = 0; j < 4; ++j) {
                float v = fmaxf(acc[mi][ni][j] + bb[ni], 0.f);
                const int rl = wr + mi * 16 + orow4 + j;
                const int cl = wc + ni * 16 + col;
                Ys[(rl * 128 + cl) ^ ((rl & 15) << 3)] = f2bf(v);
            }
    __syncthreads();

    {
        const int r = tid >> 2, c = (tid & 3) * 32;
        const int swz = (r & 15) << 3;
        ushort* Yg = Y + (size_t)(row0 + r) * 128 + c;
        #pragma unroll
        for (int j = 0; j < 4; ++j)
            *(uint4*)&Yg[j * 8] = *(const uint4*)&Ys[(r * 128 + c + j * 8) ^ swz];
    }
}

// ---------------------------------------------------------------------------
// ktv: per (batch, 64-row chunk): partial Mt_part[v][e] = sum_r v[r][v]*k[r][e]
// ---------------------------------------------------------------------------
__global__ __launch_bounds__(256) void ktv_kernel(
    const ushort* __restrict__ kp, const ushort* __restrict__ vp,
    ushort* __restrict__ part)
{
    const int b = blockIdx.y, chunk = blockIdx.x;
    const ushort* K = kp + ((size_t)b * LK + chunk * 64) * 128;
    const ushort* V = vp + ((size_t)b * LK + chunk * 64) * 128;
    ushort* P = part + ((size_t)(b * 32 + chunk)) * 16384;

    __shared__ __align__(16) ushort ks[64 * 128];
    __shared__ __align__(16) ushort vs[64 * 128];
    const int t = threadIdx.x;
    {
        const int r = t >> 2, cc = (t & 3) * 32;
        #pragma unroll
        for (int j = 0; j < 4; ++j) {
            *(uint4*)&ks[r * 128 + cc + j * 8] = *(const uint4*)&K[r * 128 + cc + j * 8];
            *(uint4*)&vs[r * 128 + cc + j * 8] = *(const uint4*)&V[r * 128 + cc + j * 8];
        }
    }
    __syncthreads();

    const int e0 = (t & 15) * 8;
    const int v0 = (t >> 4) * 8;
    float acc[8][8];
    #pragma unroll
    for (int i = 0; i < 8; ++i)
        #pragma unroll
        for (int j = 0; j < 8; ++j) acc[i][j] = 0.f;

    for (int r = 0; r < 64; ++r) {
        uint4 kf = *(const uint4*)&ks[r * 128 + e0];
        uint4 vf = *(const uint4*)&vs[r * 128 + v0];
        const ushort* kw = (const ushort*)&kf;
        const ushort* vw = (const ushort*)&vf;
        float ke[8], ve[8];
        #pragma unroll
        for (int j = 0; j < 8; ++j) { ke[j] = bf2f(kw[j]); ve[j] = bf2f(vw[j]); }
        #pragma unroll
        for (int i = 0; i < 8; ++i)
            #pragma unroll
            for (int j = 0; j < 8; ++j)
                acc[i][j] = fmaf(ve[i], ke[j], acc[i][j]);
    }

    #pragma unroll
    for (int i = 0; i < 8; ++i) {
        ushort tmp[8];
        #pragma unroll
        for (int j = 0; j < 8; ++j) tmp[j] = f2bf(acc[i][j]);
        *(uint4*)&P[(v0 + i) * 128 + e0] = *(uint4*)&tmp[0];
    }
}

// ---------------------------------------------------------------------------
// reduce: Mt[b][v*128+e] = bf16(KSCALE * sum_{c<32} part[b][c][v*128+e])
// ---------------------------------------------------------------------------
__global__ __launch_bounds__(256) void reduce_kernel(
    const ushort* __restrict__ part, ushort* __restrict__ Mt)
{
    const int g = blockIdx.x * 256 + threadIdx.x;
    const int b = g >> 14, idx = g & 16383;
    const ushort* P = part + (size_t)b * 32 * 16384 + idx;
    float s = 0.f;
    #pragma unroll
    for (int c = 0; c < 32; ++c) s += bf2f(P[(size_t)c * 16384]);
    Mt[g] = f2bf(s * KSCALE);
}

// ---------------------------------------------------------------------------
// qm: out[row][v] = sum_e qp[row][e] * Mt[b][v][e]
// ---------------------------------------------------------------------------
__global__ __launch_bounds__(256) void qm_kernel(
    const ushort* __restrict__ qp, const ushort* __restrict__ Mt,
    float* __restrict__ out)
{
    const int row0 = blockIdx.x * 64;
    const int b = row0 >> 11;
    const ushort* Q = qp + (size_t)row0 * 128;
    const ushort* M = Mt + (size_t)b * 16384;

    __shared__ __align__(16) ushort As[64 * 128];
    __shared__ __align__(16) ushort Bs[128 * 128];

    const int t = threadIdx.x;
    {
        const int r = t >> 2, cc = (t & 3) * 32;
        const int swz = (r & 15) << 3;
        #pragma unroll
        for (int j = 0; j < 4; ++j)
            *(uint4*)&As[(r * 128 + cc + j * 8) ^ swz] = *(const uint4*)&Q[r * 128 + cc + j * 8];
    }
    {
        const int r = t >> 1, cc = (t & 1) * 64;
        const int swz = (r & 15) << 3;
        #pragma unroll
        for (int j = 0; j < 8; ++j)
            *(uint4*)&Bs[(r * 128 + cc + j * 8) ^ swz] = *(const uint4*)&M[r * 128 + cc + j * 8];
    }
    __syncthreads();

    const int lane = t & 63;
    const int wcol = (t >> 6) * 32;
    const int col  = lane & 15;
    const int kgrp = (lane >> 4) * 8;
    const int fswz = col << 3;

    f32x4 acc[4][2];
    #pragma unroll
    for (int mi = 0; mi < 4; ++mi)
        #pragma unroll
        for (int ni = 0; ni < 2; ++ni)
            acc[mi][ni] = (f32x4){0.f, 0.f, 0.f, 0.f};

    #pragma unroll
    for (int kk = 0; kk < 4; ++kk) {
        const int kb = kk * 32 + kgrp;
        short8 af[4], bfv[2];
        #pragma unroll
        for (int mi = 0; mi < 4; ++mi)
            af[mi] = *(const short8*)&As[((mi * 16 + col) * 128 + kb) ^ fswz];
        #pragma unroll
        for (int ni = 0; ni < 2; ++ni)
            bfv[ni] = *(const short8*)&Bs[((wcol + ni * 16 + col) * 128 + kb) ^ fswz];
        #pragma unroll
        for (int mi = 0; mi < 4; ++mi)
            #pragma unroll
            for (int ni = 0; ni < 2; ++ni)
                acc[mi][ni] = __builtin_amdgcn_mfma_f32_16x16x32_bf16(
                    af[mi], bfv[ni], acc[mi][ni], 0, 0, 0);
    }

    const int orow = (lane >> 4) * 4;
    #pragma unroll
    for (int mi = 0; mi < 4; ++mi)
        #pragma unroll
        for (int ni = 0; ni < 2; ++ni)
            #pragma unroll
            for (int j = 0; j < 4; ++j)
                out[(size_t)(row0 + mi * 16 + orow + j) * 128 + wcol + ni * 16 + col] =
                    acc[mi][ni][j];
}

// ---------------------------------------------------------------------------
extern "C" void kernel_launch(void* const* d_in, const int* in_sizes, int n_in,
                              void* d_out, int out_size, void* d_ws, size_t ws_size,
                              hipStream_t stream)
{
    const float* query = (const float*)d_in[0];
    const float* key   = (const float*)d_in[1];
    const float* value = (const float*)d_in[2];
    const float* Wq    = (const float*)d_in[3];
    const float* bq    = (const float*)d_in[4];
    const float* Wk    = (const float*)d_in[5];
    const float* bk    = (const float*)d_in[6];
    const float* Wv    = (const float*)d_in[7];
    const float* bv    = (const float*)d_in[8];
    float* out = (float*)d_out;

    ushort* qp   = (ushort*)d_ws;                    // 16384*128 bf16
    ushort* kp   = qp + (size_t)MROWS * 128;
    ushort* vp   = kp + (size_t)MROWS * 128;
    ushort* Wt   = vp + (size_t)MROWS * 128;         // 3*128*1024 bf16
    ushort* part = Wt + (size_t)3 * 128 * 1024;      // 8*32*16384 bf16
    ushort* Mt   = part + (size_t)8 * 32 * 16384;    // 8*16384 bf16

    dim3 blk(256);
    prep_kernel<<<dim3(16, 2, 3), blk, 0, stream>>>(Wq, Wk, Wv, Wt);
    proj_kernel<<<dim3(256, 3), blk, 0, stream>>>(query, bq, key, bk, value, bv,
                                                  Wt, qp, kp, vp);
    ktv_kernel<<<dim3(32, NB), blk, 0, stream>>>(kp, vp, part);
    reduce_kernel<<<512, blk, 0, stream>>>(part, Mt);
    qm_kernel<<<MROWS / 64, blk, 0, stream>>>(qp, Mt, out);
}